// Round 1
// baseline (262.201 us; speedup 1.0000x reference)
//
#include <hip/hip_runtime.h>
#include <math.h>

#define CB 8
#define CNX 512
#define CNR 512
#define CD 256
#define CH 256

__device__ __forceinline__ float fast_rcp(float x) {
#if __has_builtin(__builtin_amdgcn_rcpf)
  return __builtin_amdgcn_rcpf(x);
#else
  return 1.0f / x;
#endif
}
__device__ __forceinline__ float fast_exp2(float x) {
#if __has_builtin(__builtin_amdgcn_exp2f)
  return __builtin_amdgcn_exp2f(x);
#else
  return exp2f(x);
#endif
}

// C[m][n] = bias[n] + sum_k A[m][k] * W[n][k]
// A: (4096 x 256) row-major, W: (256 x 256) row-major, C: (4096 x 256)
// grid (M/64, N/64), block 256
__global__ __launch_bounds__(256) void proj_gemm_nt(
    const float* __restrict__ A, const float* __restrict__ W,
    const float* __restrict__ bias, float* __restrict__ C) {
  __shared__ float As[16][64];  // [k][m]
  __shared__ float Ws[16][64];  // [k][n]
  const int K = CD;
  int m0 = blockIdx.x * 64, n0 = blockIdx.y * 64;
  int tid = threadIdx.x;
  int tx = tid & 15, ty = tid >> 4;   // tx -> n, ty -> m
  int lrow = tid >> 2, lc4 = tid & 3;
  float acc[4][4] = {};
  const float* pA = A + (size_t)(m0 + lrow) * K + lc4 * 4;
  const float* pW = W + (size_t)(n0 + lrow) * K + lc4 * 4;
  for (int kt = 0; kt < K; kt += 16) {
    float4 av = *(const float4*)(pA + kt);
    float4 wv = *(const float4*)(pW + kt);
    __syncthreads();
    As[lc4 * 4 + 0][lrow] = av.x;
    As[lc4 * 4 + 1][lrow] = av.y;
    As[lc4 * 4 + 2][lrow] = av.z;
    As[lc4 * 4 + 3][lrow] = av.w;
    Ws[lc4 * 4 + 0][lrow] = wv.x;
    Ws[lc4 * 4 + 1][lrow] = wv.y;
    Ws[lc4 * 4 + 2][lrow] = wv.z;
    Ws[lc4 * 4 + 3][lrow] = wv.w;
    __syncthreads();
#pragma unroll
    for (int k = 0; k < 16; k++) {
      float4 a4 = *(const float4*)&As[k][ty * 4];
      float4 w4 = *(const float4*)&Ws[k][tx * 4];
      float am[4] = {a4.x, a4.y, a4.z, a4.w};
      float wm[4] = {w4.x, w4.y, w4.z, w4.w};
#pragma unroll
      for (int i = 0; i < 4; i++)
#pragma unroll
        for (int j = 0; j < 4; j++)
          acc[i][j] = fmaf(am[i], wm[j], acc[i][j]);
    }
  }
  float4 bv = *(const float4*)(bias + n0 + tx * 4);
  float bm[4] = {bv.x, bv.y, bv.z, bv.w};
  float* pC = C + (size_t)(m0 + ty * 4) * CH + n0 + tx * 4;
#pragma unroll
  for (int i = 0; i < 4; i++) {
    float4 o = {acc[i][0] + bm[0], acc[i][1] + bm[1],
                acc[i][2] + bm[2], acc[i][3] + bm[3]};
    *(float4*)(pC + (size_t)i * CH) = o;
  }
}

// scoresT[b][r][x] = v_b + sum_h v_w[h] * tanh(hX[b][x][h] + hR[b][r][h])
// grid (NX/64, NR/64, B), block 256; each thread computes a 4(r)x4(x) microtile
__global__ __launch_bounds__(256) void scores_kernel(
    const float* __restrict__ hX, const float* __restrict__ hR,
    const float* __restrict__ v_w, const float* __restrict__ v_b,
    float* __restrict__ scT) {
  __shared__ float xs[64][64];  // [h][x]
  __shared__ float rs[64][64];  // [h][r]
  __shared__ float vsh[CH];
  int b = blockIdx.z;
  int x0 = blockIdx.x * 64, r0 = blockIdx.y * 64;
  int tid = threadIdx.x;
  int tx = tid & 15, ty = tid >> 4;  // tx -> x, ty -> r
  vsh[tid] = v_w[tid];
  const float* pX = hX + ((size_t)b * CNX + x0) * CH;
  const float* pR = hR + ((size_t)b * CNR + r0) * CH;
  float acc[4][4] = {};
  const float K2L = 2.8853900817779268f;  // 2*log2(e)
  for (int hc = 0; hc < CH; hc += 64) {
    float4 xv[4], rv[4];
#pragma unroll
    for (int p = 0; p < 4; p++) {
      int idx = tid + p * 256;
      int row = idx >> 4, c4 = idx & 15;
      xv[p] = *(const float4*)(pX + (size_t)row * CH + hc + c4 * 4);
      rv[p] = *(const float4*)(pR + (size_t)row * CH + hc + c4 * 4);
    }
    __syncthreads();
#pragma unroll
    for (int p = 0; p < 4; p++) {
      int idx = tid + p * 256;
      int row = idx >> 4, c4 = idx & 15;
      xs[c4 * 4 + 0][row] = xv[p].x;
      xs[c4 * 4 + 1][row] = xv[p].y;
      xs[c4 * 4 + 2][row] = xv[p].z;
      xs[c4 * 4 + 3][row] = xv[p].w;
      rs[c4 * 4 + 0][row] = rv[p].x;
      rs[c4 * 4 + 1][row] = rv[p].y;
      rs[c4 * 4 + 2][row] = rv[p].z;
      rs[c4 * 4 + 3][row] = rv[p].w;
    }
    __syncthreads();
#pragma unroll 4
    for (int h = 0; h < 64; h++) {
      float4 x4 = *(const float4*)&xs[h][tx * 4];
      float4 r4 = *(const float4*)&rs[h][ty * 4];
      float vh = vsh[hc + h];
      float xm[4] = {x4.x, x4.y, x4.z, x4.w};
      float rm[4] = {r4.x, r4.y, r4.z, r4.w};
#pragma unroll
      for (int i = 0; i < 4; i++)
#pragma unroll
        for (int j = 0; j < 4; j++) {
          float s = rm[i] + xm[j];
          // tanh(s) = 1 - 2/(exp(2s)+1), exp(2s) = exp2(s*2*log2e)
          float e = fast_exp2(s * K2L);
          float t = fmaf(-2.0f, fast_rcp(e + 1.0f), 1.0f);
          acc[i][j] = fmaf(vh, t, acc[i][j]);
        }
    }
  }
  float vb = v_b[0];
  float* pO = scT + ((size_t)b * CNR + r0 + ty * 4) * CNX + x0 + tx * 4;
#pragma unroll
  for (int i = 0; i < 4; i++) {
    float4 o = {acc[i][0] + vb, acc[i][1] + vb, acc[i][2] + vb, acc[i][3] + vb};
    *(float4*)(pO + (size_t)i * CNX) = o;
  }
}

// in-place softmax over the contiguous x axis of scT[b][r][x]
// grid (B*NR), block 256 (2 elements per thread)
__global__ __launch_bounds__(256) void softmax_x(float* __restrict__ sc) {
  int row = blockIdx.x;
  float* p = sc + (size_t)row * CNX;
  int t = threadIdx.x;
  float a = p[t], c = p[t + 256];
  float m = fmaxf(a, c);
#pragma unroll
  for (int off = 32; off > 0; off >>= 1) m = fmaxf(m, __shfl_xor(m, off, 64));
  __shared__ float redm[4], reds[4];
  int wave = t >> 6, lane = t & 63;
  if (lane == 0) redm[wave] = m;
  __syncthreads();
  m = fmaxf(fmaxf(redm[0], redm[1]), fmaxf(redm[2], redm[3]));
  const float L2E = 1.4426950408889634f;
  float e0 = fast_exp2((a - m) * L2E);
  float e1 = fast_exp2((c - m) * L2E);
  float s = e0 + e1;
#pragma unroll
  for (int off = 32; off > 0; off >>= 1) s += __shfl_xor(s, off, 64);
  if (lane == 0) reds[wave] = s;
  __syncthreads();
  s = (reds[0] + reds[1]) + (reds[2] + reds[3]);
  float inv = fast_rcp(s);
  p[t] = e0 * inv;
  p[t + 256] = e1 * inv;
}

// out[b][r][d] = sum_x at[b][r][x] * X[b][x][d]
// grid (NR/64, D/64, B), block 256
__global__ __launch_bounds__(256) void wsum_gemm(
    const float* __restrict__ at, const float* __restrict__ X,
    float* __restrict__ out) {
  __shared__ float As[16][64];  // [k][r]
  __shared__ float Bs[16][64];  // [k][d]
  int b = blockIdx.z;
  int r0 = blockIdx.x * 64, d0 = blockIdx.y * 64;
  int tid = threadIdx.x;
  int tx = tid & 15, ty = tid >> 4;  // tx -> d, ty -> r
  int arow = tid >> 2, ac4 = tid & 3;
  int bk = tid >> 4, bc4 = tid & 15;
  const float* pA = at + ((size_t)b * CNR + r0 + arow) * CNX + ac4 * 4;
  const float* pB = X + ((size_t)b * CNX + bk) * CD + d0 + bc4 * 4;
  float acc[4][4] = {};
  for (int kt = 0; kt < CNX; kt += 16) {
    float4 av = *(const float4*)(pA + kt);
    float4 bv = *(const float4*)(pB + (size_t)kt * CD);
    __syncthreads();
    As[ac4 * 4 + 0][arow] = av.x;
    As[ac4 * 4 + 1][arow] = av.y;
    As[ac4 * 4 + 2][arow] = av.z;
    As[ac4 * 4 + 3][arow] = av.w;
    *(float4*)&Bs[bk][bc4 * 4] = bv;
    __syncthreads();
#pragma unroll
    for (int k = 0; k < 16; k++) {
      float4 a4 = *(const float4*)&As[k][ty * 4];
      float4 b4 = *(const float4*)&Bs[k][tx * 4];
      float am[4] = {a4.x, a4.y, a4.z, a4.w};
      float bm[4] = {b4.x, b4.y, b4.z, b4.w};
#pragma unroll
      for (int i = 0; i < 4; i++)
#pragma unroll
        for (int j = 0; j < 4; j++)
          acc[i][j] = fmaf(am[i], bm[j], acc[i][j]);
    }
  }
  float* pO = out + ((size_t)b * CNR + r0 + ty * 4) * CD + d0 + tx * 4;
#pragma unroll
  for (int i = 0; i < 4; i++) {
    float4 o = {acc[i][0], acc[i][1], acc[i][2], acc[i][3]};
    *(float4*)(pO + (size_t)i * CD) = o;
  }
}

extern "C" void kernel_launch(void* const* d_in, const int* in_sizes, int n_in,
                              void* d_out, int out_size, void* d_ws, size_t ws_size,
                              hipStream_t stream) {
  const float* X     = (const float*)d_in[0];
  const float* ref   = (const float*)d_in[1];
  const float* W_X   = (const float*)d_in[2];
  const float* b_X   = (const float*)d_in[3];
  const float* W_ref = (const float*)d_in[4];
  const float* b_ref = (const float*)d_in[5];
  const float* v_w   = (const float*)d_in[6];
  const float* v_b   = (const float*)d_in[7];
  float* out = (float*)d_out;
  float* ws  = (float*)d_ws;

  float* hXb = ws;                       // 4096*256 = 1,048,576 floats
  float* hRb = ws + 1048576;             // 1,048,576 floats
  float* scT = ws + 2097152;             // B*NR*NX = 2,097,152 floats
  // total workspace: 16 MiB

  // hX = X @ W_X^T + b_X ; hR = ref @ W_ref^T + b_ref
  proj_gemm_nt<<<dim3(64, 4, 1), 256, 0, stream>>>(X, W_X, b_X, hXb);
  proj_gemm_nt<<<dim3(64, 4, 1), 256, 0, stream>>>(ref, W_ref, b_ref, hRb);
  // scoresT[b][r][x]
  scores_kernel<<<dim3(8, 8, 8), 256, 0, stream>>>(hXb, hRb, v_w, v_b, scT);
  // softmax over x (contiguous rows)
  softmax_x<<<dim3(CB * CNR, 1, 1), 256, 0, stream>>>(scT);
  // out[b][r][d] = sum_x attn[b][r][x] * X[b][x][d]
  wsum_gemm<<<dim3(8, 4, 8), 256, 0, stream>>>(scT, X, out);
}

// Round 2
// 200.757 us; speedup vs baseline: 1.3061x; 1.3061x over previous
//
#include <hip/hip_runtime.h>
#include <math.h>

#define CB 8
#define CNX 512
#define CNR 512
#define CD 256
#define CH 256

__device__ __forceinline__ float fast_rcp(float x) {
#if __has_builtin(__builtin_amdgcn_rcpf)
  return __builtin_amdgcn_rcpf(x);
#else
  return 1.0f / x;
#endif
}
__device__ __forceinline__ float fast_exp2(float x) {
#if __has_builtin(__builtin_amdgcn_exp2f)
  return __builtin_amdgcn_exp2f(x);
#else
  return exp2f(x);
#endif
}

// ET[b][h][x] = exp2(K2L * (sum_k A[m][k]*W[h][k] + bias[h])), m = b*512 + x
// A: (4096 x 256) row-major, W: (256 x 256) row-major
// grid (M/64, H/64), block 256
__global__ __launch_bounds__(256) void proj_gemm_exp_t(
    const float* __restrict__ A, const float* __restrict__ W,
    const float* __restrict__ bias, float* __restrict__ ET) {
  __shared__ float As[16][68];  // [k][m], padded
  __shared__ float Ws[16][68];  // [k][n], padded
  const int K = CD;
  int m0 = blockIdx.x * 64, n0 = blockIdx.y * 64;
  int tid = threadIdx.x;
  int tx = tid & 15, ty = tid >> 4;   // tx -> n(h), ty -> m(x)
  int lrow = tid >> 2, lc4 = tid & 3;
  float acc[4][4] = {};
  const float* pA = A + (size_t)(m0 + lrow) * K + lc4 * 4;
  const float* pW = W + (size_t)(n0 + lrow) * K + lc4 * 4;
  for (int kt = 0; kt < K; kt += 16) {
    float4 av = *(const float4*)(pA + kt);
    float4 wv = *(const float4*)(pW + kt);
    __syncthreads();
    As[lc4 * 4 + 0][lrow] = av.x;
    As[lc4 * 4 + 1][lrow] = av.y;
    As[lc4 * 4 + 2][lrow] = av.z;
    As[lc4 * 4 + 3][lrow] = av.w;
    Ws[lc4 * 4 + 0][lrow] = wv.x;
    Ws[lc4 * 4 + 1][lrow] = wv.y;
    Ws[lc4 * 4 + 2][lrow] = wv.z;
    Ws[lc4 * 4 + 3][lrow] = wv.w;
    __syncthreads();
#pragma unroll
    for (int k = 0; k < 16; k++) {
      float4 a4 = *(const float4*)&As[k][ty * 4];
      float4 w4 = *(const float4*)&Ws[k][tx * 4];
      float am[4] = {a4.x, a4.y, a4.z, a4.w};
      float wm[4] = {w4.x, w4.y, w4.z, w4.w};
#pragma unroll
      for (int i = 0; i < 4; i++)
#pragma unroll
        for (int j = 0; j < 4; j++)
          acc[i][j] = fmaf(am[i], wm[j], acc[i][j]);
    }
  }
  const float K2L = 2.8853900817779268f;  // 2*log2(e)
  float4 bv = *(const float4*)(bias + n0 + tx * 4);
  float bm[4] = {bv.x, bv.y, bv.z, bv.w};
  int b = m0 >> 9;
  int x = (m0 & 511) + ty * 4;
#pragma unroll
  for (int j = 0; j < 4; j++) {
    int h = n0 + tx * 4 + j;
    float4 o = {fast_exp2(K2L * (acc[0][j] + bm[j])),
                fast_exp2(K2L * (acc[1][j] + bm[j])),
                fast_exp2(K2L * (acc[2][j] + bm[j])),
                fast_exp2(K2L * (acc[3][j] + bm[j]))};
    *(float4*)(ET + ((size_t)b * CH + h) * CNX + x) = o;
  }
}

// scT[b][r][x] = -2 * sum_h v_w[h] / (exT[b][h][x]*erT[b][h][r] + 1)
// (true score differs by a constant per-(b,r)? no — constant vb+sum(v) is
//  uniform over x, and softmax over x is shift-invariant, so it drops)
// grid (NX/64, NR/64, B), block 256; 4(r)x4(x) microtile per thread
__global__ __launch_bounds__(256) void scores_kernel(
    const float* __restrict__ exT, const float* __restrict__ erT,
    const float* __restrict__ v_w, float* __restrict__ scT) {
  __shared__ float xs[64][64];  // [h][x]
  __shared__ float rs[64][64];  // [h][r]
  __shared__ float vsh[CH];
  int b = blockIdx.z;
  int x0 = blockIdx.x * 64, r0 = blockIdx.y * 64;
  int tid = threadIdx.x;
  int tx = tid & 15, ty = tid >> 4;  // tx -> x, ty -> r
  vsh[tid] = v_w[tid];
  float acc[4][4] = {};
  const float* pX = exT + (size_t)b * CH * CNX + x0;
  const float* pR = erT + (size_t)b * CH * CNX + r0;
  for (int hc = 0; hc < CH; hc += 64) {
    float4 xv[4], rv[4];
    int row = tid >> 4, c4 = tid & 15;
#pragma unroll
    for (int p = 0; p < 4; p++) {
      xv[p] = *(const float4*)(pX + (size_t)(hc + row + p * 16) * CNX + c4 * 4);
      rv[p] = *(const float4*)(pR + (size_t)(hc + row + p * 16) * CNX + c4 * 4);
    }
    __syncthreads();
#pragma unroll
    for (int p = 0; p < 4; p++) {
      *(float4*)&xs[row + p * 16][c4 * 4] = xv[p];
      *(float4*)&rs[row + p * 16][c4 * 4] = rv[p];
    }
    __syncthreads();
#pragma unroll 4
    for (int h = 0; h < 64; h++) {
      float4 x4 = *(const float4*)&xs[h][tx * 4];
      float4 r4 = *(const float4*)&rs[h][ty * 4];
      float vh = vsh[hc + h];
      float xm[4] = {x4.x, x4.y, x4.z, x4.w};
      float rm[4] = {r4.x, r4.y, r4.z, r4.w};
#pragma unroll
      for (int i = 0; i < 4; i++)
#pragma unroll
        for (int j = 0; j < 4; j++) {
          float d = fmaf(rm[i], xm[j], 1.0f);
          acc[i][j] = fmaf(vh, fast_rcp(d), acc[i][j]);
        }
    }
  }
  float* pO = scT + ((size_t)b * CNR + r0 + ty * 4) * CNX + x0 + tx * 4;
#pragma unroll
  for (int i = 0; i < 4; i++) {
    float4 o = {-2.0f * acc[i][0], -2.0f * acc[i][1],
                -2.0f * acc[i][2], -2.0f * acc[i][3]};
    *(float4*)(pO + (size_t)i * CNX) = o;
  }
}

// in-place softmax over the contiguous x axis of scT[b][r][x]
// grid (B*NR), block 256 (2 elements per thread)
__global__ __launch_bounds__(256) void softmax_x(float* __restrict__ sc) {
  int row = blockIdx.x;
  float* p = sc + (size_t)row * CNX;
  int t = threadIdx.x;
  float a = p[t], c = p[t + 256];
  float m = fmaxf(a, c);
#pragma unroll
  for (int off = 32; off > 0; off >>= 1) m = fmaxf(m, __shfl_xor(m, off, 64));
  __shared__ float redm[4], reds[4];
  int wave = t >> 6, lane = t & 63;
  if (lane == 0) redm[wave] = m;
  __syncthreads();
  m = fmaxf(fmaxf(redm[0], redm[1]), fmaxf(redm[2], redm[3]));
  const float L2E = 1.4426950408889634f;
  float e0 = fast_exp2((a - m) * L2E);
  float e1 = fast_exp2((c - m) * L2E);
  float s = e0 + e1;
#pragma unroll
  for (int off = 32; off > 0; off >>= 1) s += __shfl_xor(s, off, 64);
  if (lane == 0) reds[wave] = s;
  __syncthreads();
  s = (reds[0] + reds[1]) + (reds[2] + reds[3]);
  float inv = fast_rcp(s);
  p[t] = e0 * inv;
  p[t + 256] = e1 * inv;
}

// out[b][r][d] = sum_x at[b][r][x] * X[b][x][d]
// grid (NR/64, D/64, B), block 256
__global__ __launch_bounds__(256) void wsum_gemm(
    const float* __restrict__ at, const float* __restrict__ X,
    float* __restrict__ out) {
  __shared__ float As[16][68];  // [k][r], padded
  __shared__ float Bs[16][68];  // [k][d], padded
  int b = blockIdx.z;
  int r0 = blockIdx.x * 64, d0 = blockIdx.y * 64;
  int tid = threadIdx.x;
  int tx = tid & 15, ty = tid >> 4;  // tx -> d, ty -> r
  int arow = tid >> 2, ac4 = tid & 3;
  int bk = tid >> 4, bc4 = tid & 15;
  const float* pA = at + ((size_t)b * CNR + r0 + arow) * CNX + ac4 * 4;
  const float* pB = X + ((size_t)b * CNX + bk) * CD + d0 + bc4 * 4;
  float acc[4][4] = {};
  for (int kt = 0; kt < CNX; kt += 16) {
    float4 av = *(const float4*)(pA + kt);
    float4 bv = *(const float4*)(pB + (size_t)kt * CD);
    __syncthreads();
    As[ac4 * 4 + 0][arow] = av.x;
    As[ac4 * 4 + 1][arow] = av.y;
    As[ac4 * 4 + 2][arow] = av.z;
    As[ac4 * 4 + 3][arow] = av.w;
    *(float4*)&Bs[bk][bc4 * 4] = bv;
    __syncthreads();
#pragma unroll
    for (int k = 0; k < 16; k++) {
      float4 a4 = *(const float4*)&As[k][ty * 4];
      float4 b4 = *(const float4*)&Bs[k][tx * 4];
      float am[4] = {a4.x, a4.y, a4.z, a4.w};
      float bm[4] = {b4.x, b4.y, b4.z, b4.w};
#pragma unroll
      for (int i = 0; i < 4; i++)
#pragma unroll
        for (int j = 0; j < 4; j++)
          acc[i][j] = fmaf(am[i], bm[j], acc[i][j]);
    }
  }
  float* pO = out + ((size_t)b * CNR + r0 + ty * 4) * CD + d0 + tx * 4;
#pragma unroll
  for (int i = 0; i < 4; i++) {
    float4 o = {acc[i][0], acc[i][1], acc[i][2], acc[i][3]};
    *(float4*)(pO + (size_t)i * CD) = o;
  }
}

extern "C" void kernel_launch(void* const* d_in, const int* in_sizes, int n_in,
                              void* d_out, int out_size, void* d_ws, size_t ws_size,
                              hipStream_t stream) {
  const float* X     = (const float*)d_in[0];
  const float* ref   = (const float*)d_in[1];
  const float* W_X   = (const float*)d_in[2];
  const float* b_X   = (const float*)d_in[3];
  const float* W_ref = (const float*)d_in[4];
  const float* b_ref = (const float*)d_in[5];
  const float* v_w   = (const float*)d_in[6];
  float* out = (float*)d_out;
  float* ws  = (float*)d_ws;

  float* exT = ws;                       // [B][H][NX] = 1,048,576 floats
  float* erT = ws + 1048576;             // [B][H][NR] = 1,048,576 floats
  float* scT = ws + 2097152;             // [B][NR][NX] = 2,097,152 floats
  // total workspace: 16 MiB

  // exT = exp(2*hX)^T, erT = exp(2*hR)^T (transposed to [b][h][*])
  proj_gemm_exp_t<<<dim3(64, 4, 1), 256, 0, stream>>>(X, W_X, b_X, exT);
  proj_gemm_exp_t<<<dim3(64, 4, 1), 256, 0, stream>>>(ref, W_ref, b_ref, erT);
  // scT[b][r][x] = -2 * sum_h v_w[h]/(ex*er+1)  (== true score minus a
  // per-row constant, which softmax ignores)
  scores_kernel<<<dim3(8, 8, 8), 256, 0, stream>>>(exT, erT, v_w, scT);
  // softmax over x (contiguous rows)
  softmax_x<<<dim3(CB * CNR, 1, 1), 256, 0, stream>>>(scT);
  // out[b][r][d] = sum_x attn[b][r][x] * X[b][x][d]
  wsum_gemm<<<dim3(8, 4, 8), 256, 0, stream>>>(scT, X, out);
}

// Round 3
// 186.917 us; speedup vs baseline: 1.4028x; 1.0740x over previous
//
#include <hip/hip_runtime.h>
#include <math.h>

#define CB 8
#define CNX 512
#define CNR 512
#define CD 256
#define CH 256

__device__ __forceinline__ float fast_rcp(float x) {
#if __has_builtin(__builtin_amdgcn_rcpf)
  return __builtin_amdgcn_rcpf(x);
#else
  return 1.0f / x;
#endif
}
__device__ __forceinline__ float fast_exp2(float x) {
#if __has_builtin(__builtin_amdgcn_exp2f)
  return __builtin_amdgcn_exp2f(x);
#else
  return exp2f(x);
#endif
}

// ET[b][h][x] = exp2(K2L*(sum_k A[m][k]*W[h][k] + bias[h])), m = b*512+x
// 32(m) x 64(h) tile, K-tile 32, grid (M/32, H/64) = (128,4), block 256
// microtile: tx->m (2), ty->h (4)
__global__ __launch_bounds__(256) void proj_gemm_exp_t(
    const float* __restrict__ A, const float* __restrict__ W,
    const float* __restrict__ bias, float* __restrict__ ET) {
  __shared__ float As[32][33];  // [k][m]
  __shared__ float Ws[32][68];  // [k][h]
  const int K = CD;
  int m0 = blockIdx.x * 32, n0 = blockIdx.y * 64;
  int tid = threadIdx.x;
  int tx = tid & 15, ty = tid >> 4;
  int arow = tid >> 3, ak4 = tid & 7;  // A: 32 rows x 32 k
  int wrow = tid >> 3, wk4 = tid & 7;  // W: 64 rows x 32 k (2 passes)
  float acc[2][4] = {};
  for (int kt = 0; kt < K; kt += 32) {
    float4 av = *(const float4*)(A + (size_t)(m0 + arow) * K + kt + ak4 * 4);
    float4 wv0 = *(const float4*)(W + (size_t)(n0 + wrow) * K + kt + wk4 * 4);
    float4 wv1 = *(const float4*)(W + (size_t)(n0 + wrow + 32) * K + kt + wk4 * 4);
    __syncthreads();
    As[ak4 * 4 + 0][arow] = av.x;
    As[ak4 * 4 + 1][arow] = av.y;
    As[ak4 * 4 + 2][arow] = av.z;
    As[ak4 * 4 + 3][arow] = av.w;
    Ws[wk4 * 4 + 0][wrow] = wv0.x;
    Ws[wk4 * 4 + 1][wrow] = wv0.y;
    Ws[wk4 * 4 + 2][wrow] = wv0.z;
    Ws[wk4 * 4 + 3][wrow] = wv0.w;
    Ws[wk4 * 4 + 0][wrow + 32] = wv1.x;
    Ws[wk4 * 4 + 1][wrow + 32] = wv1.y;
    Ws[wk4 * 4 + 2][wrow + 32] = wv1.z;
    Ws[wk4 * 4 + 3][wrow + 32] = wv1.w;
    __syncthreads();
#pragma unroll 8
    for (int k = 0; k < 32; k++) {
      float a0 = As[k][tx * 2], a1 = As[k][tx * 2 + 1];
      float4 w4 = *(const float4*)&Ws[k][ty * 4];
      float wm[4] = {w4.x, w4.y, w4.z, w4.w};
#pragma unroll
      for (int j = 0; j < 4; j++) {
        acc[0][j] = fmaf(a0, wm[j], acc[0][j]);
        acc[1][j] = fmaf(a1, wm[j], acc[1][j]);
      }
    }
  }
  const float K2L = 2.8853900817779268f;  // 2*log2(e)
  float4 bv = *(const float4*)(bias + n0 + ty * 4);
  float bm[4] = {bv.x, bv.y, bv.z, bv.w};
  int b = m0 >> 9;
  int xbase = (m0 & 511) + tx * 2;
#pragma unroll
  for (int j = 0; j < 4; j++) {
    int h = n0 + ty * 4 + j;
    float2 o = {fast_exp2(K2L * (acc[0][j] + bm[j])),
                fast_exp2(K2L * (acc[1][j] + bm[j]))};
    *(float2*)(ET + ((size_t)b * CH + h) * CNX + xbase) = o;
  }
}

// scT[b][r][x] = -2 * sum_h v_w[h] / (exT[b][h][x]*erT[b][h][r] + 1)
// pairwise h-merge: v1/a + v2/b = (v1*b + v2*a) * rcp(a*b)
// 64(x) x 32(r) tile, grid (8,16,8) = 1024 blocks, block 256
// microtile: tx->x (4), ty->r (2)
__global__ __launch_bounds__(256) void scores_kernel(
    const float* __restrict__ exT, const float* __restrict__ erT,
    const float* __restrict__ v_w, float* __restrict__ scT) {
  __shared__ float xs[64][64];  // [h][x]
  __shared__ float rs[64][32];  // [h][r]
  __shared__ float vsh[CH];
  int b = blockIdx.z;
  int x0 = blockIdx.x * 64, r0 = blockIdx.y * 32;
  int tid = threadIdx.x;
  int tx = tid & 15, ty = tid >> 4;
  vsh[tid] = v_w[tid];
  float acc[2][4] = {};
  const float* pX = exT + (size_t)b * CH * CNX + x0;
  const float* pR = erT + (size_t)b * CH * CNR + r0;
  int xrow = tid >> 4, xc4 = tid & 15;
  int rrow = tid >> 3, rc4 = tid & 7;
  for (int hc = 0; hc < CH; hc += 64) {
    float4 xv[4], rv[2];
#pragma unroll
    for (int p = 0; p < 4; p++)
      xv[p] = *(const float4*)(pX + (size_t)(hc + xrow + p * 16) * CNX + xc4 * 4);
#pragma unroll
    for (int p = 0; p < 2; p++)
      rv[p] = *(const float4*)(pR + (size_t)(hc + rrow + p * 32) * CNR + rc4 * 4);
    __syncthreads();
#pragma unroll
    for (int p = 0; p < 4; p++)
      *(float4*)&xs[xrow + p * 16][xc4 * 4] = xv[p];
#pragma unroll
    for (int p = 0; p < 2; p++)
      *(float4*)&rs[rrow + p * 32][rc4 * 4] = rv[p];
    __syncthreads();
#pragma unroll 4
    for (int hp = 0; hp < 32; hp++) {
      int h1 = hp * 2, h2 = hp * 2 + 1;
      float4 x4a = *(const float4*)&xs[h1][tx * 4];
      float4 x4b = *(const float4*)&xs[h2][tx * 4];
      float xam[4] = {x4a.x, x4a.y, x4a.z, x4a.w};
      float xbm[4] = {x4b.x, x4b.y, x4b.z, x4b.w};
      float ram[2] = {rs[h1][ty * 2], rs[h1][ty * 2 + 1]};
      float rbm[2] = {rs[h2][ty * 2], rs[h2][ty * 2 + 1]};
      float v1 = vsh[hc + h1], v2 = vsh[hc + h2];
#pragma unroll
      for (int i = 0; i < 2; i++)
#pragma unroll
        for (int j = 0; j < 4; j++) {
          float a = fmaf(ram[i], xam[j], 1.0f);
          float bb = fmaf(rbm[i], xbm[j], 1.0f);
          float num = fmaf(v2, a, v1 * bb);
          acc[i][j] = fmaf(num, fast_rcp(a * bb), acc[i][j]);
        }
    }
  }
  float* pO = scT + ((size_t)b * CNR + r0 + ty * 2) * CNX + x0 + tx * 4;
#pragma unroll
  for (int i = 0; i < 2; i++) {
    float4 o = {-2.0f * acc[i][0], -2.0f * acc[i][1],
                -2.0f * acc[i][2], -2.0f * acc[i][3]};
    *(float4*)(pO + (size_t)i * CNX) = o;
  }
}

// in-place softmax over the contiguous x axis of scT[b][r][x]
__global__ __launch_bounds__(256) void softmax_x(float* __restrict__ sc) {
  int row = blockIdx.x;
  float* p = sc + (size_t)row * CNX;
  int t = threadIdx.x;
  float a = p[t], c = p[t + 256];
  float m = fmaxf(a, c);
#pragma unroll
  for (int off = 32; off > 0; off >>= 1) m = fmaxf(m, __shfl_xor(m, off, 64));
  __shared__ float redm[4], reds[4];
  int wave = t >> 6, lane = t & 63;
  if (lane == 0) redm[wave] = m;
  __syncthreads();
  m = fmaxf(fmaxf(redm[0], redm[1]), fmaxf(redm[2], redm[3]));
  const float L2E = 1.4426950408889634f;
  float e0 = fast_exp2((a - m) * L2E);
  float e1 = fast_exp2((c - m) * L2E);
  float s = e0 + e1;
#pragma unroll
  for (int off = 32; off > 0; off >>= 1) s += __shfl_xor(s, off, 64);
  if (lane == 0) reds[wave] = s;
  __syncthreads();
  s = (reds[0] + reds[1]) + (reds[2] + reds[3]);
  float inv = fast_rcp(s);
  p[t] = e0 * inv;
  p[t + 256] = e1 * inv;
}

// out[b][r][d] = sum_x at[b][r][x] * X[b][x][d]
// 32(r) x 64(d) tile, K-tile 32, grid (16,4,8) = 512 blocks
// microtile: tx->d (4), ty->r (2)
__global__ __launch_bounds__(256) void wsum_gemm(
    const float* __restrict__ at, const float* __restrict__ X,
    float* __restrict__ out) {
  __shared__ float As[32][33];  // [k][r]
  __shared__ float Bs[32][68];  // [k][d]
  int b = blockIdx.z;
  int r0 = blockIdx.x * 32, d0 = blockIdx.y * 64;
  int tid = threadIdx.x;
  int tx = tid & 15, ty = tid >> 4;
  int arow = tid >> 3, ak4 = tid & 7;   // at: 32 r-rows x 32 x
  int brow = tid >> 4, bc4 = tid & 15;  // X: 32 x-rows x 64 d (2 passes)
  float acc[2][4] = {};
  for (int kt = 0; kt < CNX; kt += 32) {
    float4 av = *(const float4*)(at + ((size_t)b * CNR + r0 + arow) * CNX + kt + ak4 * 4);
    float4 bv0 = *(const float4*)(X + ((size_t)b * CNX + kt + brow) * CD + d0 + bc4 * 4);
    float4 bv1 = *(const float4*)(X + ((size_t)b * CNX + kt + brow + 16) * CD + d0 + bc4 * 4);
    __syncthreads();
    As[ak4 * 4 + 0][arow] = av.x;
    As[ak4 * 4 + 1][arow] = av.y;
    As[ak4 * 4 + 2][arow] = av.z;
    As[ak4 * 4 + 3][arow] = av.w;
    *(float4*)&Bs[brow][bc4 * 4] = bv0;
    *(float4*)&Bs[brow + 16][bc4 * 4] = bv1;
    __syncthreads();
#pragma unroll 8
    for (int k = 0; k < 32; k++) {
      float a0 = As[k][ty * 2], a1 = As[k][ty * 2 + 1];
      float4 b4 = *(const float4*)&Bs[k][tx * 4];
      float bm[4] = {b4.x, b4.y, b4.z, b4.w};
#pragma unroll
      for (int j = 0; j < 4; j++) {
        acc[0][j] = fmaf(a0, bm[j], acc[0][j]);
        acc[1][j] = fmaf(a1, bm[j], acc[1][j]);
      }
    }
  }
  float* pO = out + ((size_t)b * CNR + r0 + ty * 2) * CD + d0 + tx * 4;
#pragma unroll
  for (int i = 0; i < 2; i++) {
    float4 o = {acc[i][0], acc[i][1], acc[i][2], acc[i][3]};
    *(float4*)(pO + (size_t)i * CD) = o;
  }
}

extern "C" void kernel_launch(void* const* d_in, const int* in_sizes, int n_in,
                              void* d_out, int out_size, void* d_ws, size_t ws_size,
                              hipStream_t stream) {
  const float* X     = (const float*)d_in[0];
  const float* ref   = (const float*)d_in[1];
  const float* W_X   = (const float*)d_in[2];
  const float* b_X   = (const float*)d_in[3];
  const float* W_ref = (const float*)d_in[4];
  const float* b_ref = (const float*)d_in[5];
  const float* v_w   = (const float*)d_in[6];
  float* out = (float*)d_out;
  float* ws  = (float*)d_ws;

  float* exT = ws;                       // [B][H][NX] = 1,048,576 floats
  float* erT = ws + 1048576;             // [B][H][NR] = 1,048,576 floats
  float* scT = ws + 2097152;             // [B][NR][NX] = 2,097,152 floats

  proj_gemm_exp_t<<<dim3(128, 4, 1), 256, 0, stream>>>(X, W_X, b_X, exT);
  proj_gemm_exp_t<<<dim3(128, 4, 1), 256, 0, stream>>>(ref, W_ref, b_ref, erT);
  scores_kernel<<<dim3(8, 16, 8), 256, 0, stream>>>(exT, erT, v_w, scT);
  softmax_x<<<dim3(CB * CNR, 1, 1), 256, 0, stream>>>(scT);
  wsum_gemm<<<dim3(16, 4, 8), 256, 0, stream>>>(scT, X, out);
}

// Round 4
// 161.527 us; speedup vs baseline: 1.6233x; 1.1572x over previous
//
#include <hip/hip_runtime.h>
#include <math.h>

#define CB 8
#define CNX 512
#define CNR 512
#define CD 256
#define CH 256

__device__ __forceinline__ float fast_rcp(float x) {
#if __has_builtin(__builtin_amdgcn_rcpf)
  return __builtin_amdgcn_rcpf(x);
#else
  return 1.0f / x;
#endif
}
__device__ __forceinline__ float fast_exp2(float x) {
#if __has_builtin(__builtin_amdgcn_exp2f)
  return __builtin_amdgcn_exp2f(x);
#else
  return exp2f(x);
#endif
}

// Fused projections: z=0 -> exp(2*(X@W_X^T+b_X))^T, z=1 -> same for ref.
// ET[b][h][x] = exp2(K2L*(sum_k A[m][k]*W[h][k] + bias[h])), m=b*512+x
// 64(m) x 64(h) tile, K-tile 16, grid (64,4,2), block 256, 4x4 microtile
__global__ __launch_bounds__(256) void proj_fused(
    const float* __restrict__ A0, const float* __restrict__ A1,
    const float* __restrict__ W0, const float* __restrict__ W1,
    const float* __restrict__ bias0, const float* __restrict__ bias1,
    float* __restrict__ E0, float* __restrict__ E1) {
  __shared__ float As[16][68];  // [k][m] padded
  __shared__ float Ws[16][68];  // [k][h] padded
  const int K = CD;
  int z = blockIdx.z;
  const float* A = z ? A1 : A0;
  const float* W = z ? W1 : W0;
  const float* bias = z ? bias1 : bias0;
  float* ET = z ? E1 : E0;
  int m0 = blockIdx.x * 64, n0 = blockIdx.y * 64;
  int tid = threadIdx.x;
  int tx = tid & 15, ty = tid >> 4;  // tx -> h, ty -> m(x)
  int lrow = tid >> 2, lc4 = tid & 3;
  float acc[4][4] = {};
  const float* pA = A + (size_t)(m0 + lrow) * K + lc4 * 4;
  const float* pW = W + (size_t)(n0 + lrow) * K + lc4 * 4;
  for (int kt = 0; kt < K; kt += 16) {
    float4 av = *(const float4*)(pA + kt);
    float4 wv = *(const float4*)(pW + kt);
    __syncthreads();
    As[lc4 * 4 + 0][lrow] = av.x;
    As[lc4 * 4 + 1][lrow] = av.y;
    As[lc4 * 4 + 2][lrow] = av.z;
    As[lc4 * 4 + 3][lrow] = av.w;
    Ws[lc4 * 4 + 0][lrow] = wv.x;
    Ws[lc4 * 4 + 1][lrow] = wv.y;
    Ws[lc4 * 4 + 2][lrow] = wv.z;
    Ws[lc4 * 4 + 3][lrow] = wv.w;
    __syncthreads();
#pragma unroll
    for (int k = 0; k < 16; k++) {
      float4 a4 = *(const float4*)&As[k][ty * 4];
      float4 w4 = *(const float4*)&Ws[k][tx * 4];
      float am[4] = {a4.x, a4.y, a4.z, a4.w};
      float wm[4] = {w4.x, w4.y, w4.z, w4.w};
#pragma unroll
      for (int i = 0; i < 4; i++)
#pragma unroll
        for (int j = 0; j < 4; j++)
          acc[i][j] = fmaf(am[i], wm[j], acc[i][j]);
    }
  }
  const float K2L = 2.8853900817779268f;  // 2*log2(e)
  float4 bv = *(const float4*)(bias + n0 + tx * 4);
  float bm[4] = {bv.x, bv.y, bv.z, bv.w};
  int b = m0 >> 9;
  int xbase = (m0 & 511) + ty * 4;
#pragma unroll
  for (int j = 0; j < 4; j++) {
    int h = n0 + tx * 4 + j;
    float4 o = {fast_exp2(K2L * (acc[0][j] + bm[j])),
                fast_exp2(K2L * (acc[1][j] + bm[j])),
                fast_exp2(K2L * (acc[2][j] + bm[j])),
                fast_exp2(K2L * (acc[3][j] + bm[j]))};
    *(float4*)(ET + ((size_t)b * CH + h) * CNX + xbase) = o;
  }
}

// scT[b][r][x] = -2 * sum_h v_w[h] / (exT[b][h][x]*erT[b][h][r] + 1)
// 4-way h-merge: sum v_i/a_i over 4 h via pairwise num/den combine.
// 32(x) x 32(r) tile, grid (16,16,8)=2048 blocks, block 256
// microtile: tx->x (2), ty->r (2)
__global__ __launch_bounds__(256) void scores_kernel(
    const float* __restrict__ exT, const float* __restrict__ erT,
    const float* __restrict__ v_w, float* __restrict__ scT) {
  __shared__ float xs[64][32];  // [h][x]
  __shared__ float rs[64][32];  // [h][r]
  __shared__ float vsh[CH];
  int b = blockIdx.z;
  int x0 = blockIdx.x * 32, r0 = blockIdx.y * 32;
  int tid = threadIdx.x;
  int tx = tid & 15, ty = tid >> 4;
  vsh[tid] = v_w[tid];
  float acc[2][2] = {};
  const float* pX = exT + (size_t)b * CH * CNX + x0;
  const float* pR = erT + (size_t)b * CH * CNR + r0;
  int srow = tid >> 3, sc4 = tid & 7;  // 32 h-rows x 8 float4
  for (int hc = 0; hc < CH; hc += 64) {
    float4 xv0 = *(const float4*)(pX + (size_t)(hc + srow) * CNX + sc4 * 4);
    float4 xv1 = *(const float4*)(pX + (size_t)(hc + srow + 32) * CNX + sc4 * 4);
    float4 rv0 = *(const float4*)(pR + (size_t)(hc + srow) * CNR + sc4 * 4);
    float4 rv1 = *(const float4*)(pR + (size_t)(hc + srow + 32) * CNR + sc4 * 4);
    __syncthreads();
    *(float4*)&xs[srow][sc4 * 4] = xv0;
    *(float4*)&xs[srow + 32][sc4 * 4] = xv1;
    *(float4*)&rs[srow][sc4 * 4] = rv0;
    *(float4*)&rs[srow + 32][sc4 * 4] = rv1;
    __syncthreads();
#pragma unroll 4
    for (int hq = 0; hq < 16; hq++) {
      int h0 = hq * 4;
      float4 vv = *(const float4*)&vsh[hc + h0];
      float2 xa = *(const float2*)&xs[h0 + 0][tx * 2];
      float2 xb = *(const float2*)&xs[h0 + 1][tx * 2];
      float2 xc = *(const float2*)&xs[h0 + 2][tx * 2];
      float2 xd = *(const float2*)&xs[h0 + 3][tx * 2];
      float2 ra = *(const float2*)&rs[h0 + 0][ty * 2];
      float2 rb = *(const float2*)&rs[h0 + 1][ty * 2];
      float2 rc = *(const float2*)&rs[h0 + 2][ty * 2];
      float2 rd = *(const float2*)&rs[h0 + 3][ty * 2];
      float xam[2] = {xa.x, xa.y}, xbm[2] = {xb.x, xb.y};
      float xcm[2] = {xc.x, xc.y}, xdm[2] = {xd.x, xd.y};
      float ram[2] = {ra.x, ra.y}, rbm[2] = {rb.x, rb.y};
      float rcm[2] = {rc.x, rc.y}, rdm[2] = {rd.x, rd.y};
#pragma unroll
      for (int i = 0; i < 2; i++)
#pragma unroll
        for (int j = 0; j < 2; j++) {
          float a = fmaf(ram[i], xam[j], 1.0f);
          float bb = fmaf(rbm[i], xbm[j], 1.0f);
          float c = fmaf(rcm[i], xcm[j], 1.0f);
          float d = fmaf(rdm[i], xdm[j], 1.0f);
          float q12 = a * bb, q34 = c * d;
          float p12 = fmaf(vv.y, a, vv.x * bb);
          float p34 = fmaf(vv.w, c, vv.z * d);
          float num = fmaf(p34, q12, p12 * q34);
          acc[i][j] = fmaf(num, fast_rcp(q12 * q34), acc[i][j]);
        }
    }
  }
  float* pO = scT + ((size_t)b * CNR + r0 + ty * 2) * CNX + x0 + tx * 2;
#pragma unroll
  for (int i = 0; i < 2; i++) {
    float2 o = {-2.0f * acc[i][0], -2.0f * acc[i][1]};
    *(float2*)(pO + (size_t)i * CNX) = o;
  }
}

// Fused softmax + weighted sum. Scores are bounded (|s|<~26) so
// unnormalized exp(s) is fp32-safe; accumulate numerator and denominator
// in the same K-loop, divide in the epilogue.
// out[b][r][d] = sum_x e(b,r,x)*X[b][x][d] / sum_x e(b,r,x)
// 32(r) x 64(d) tile, K-tile 32, grid (16,4,8)=512 blocks
__global__ __launch_bounds__(256) void wsum_fused(
    const float* __restrict__ scT, const float* __restrict__ X,
    float* __restrict__ out) {
  __shared__ float As[32][33];  // [k][r] unnormalized attn
  __shared__ float Bs[32][68];  // [k][d]
  __shared__ float dn[32];
  const float L2E = 1.4426950408889634f;
  int b = blockIdx.z;
  int r0 = blockIdx.x * 32, d0 = blockIdx.y * 64;
  int tid = threadIdx.x;
  int tx = tid & 15, ty = tid >> 4;   // tx -> d(4), ty -> r(2)
  int arow = tid >> 3, ak4 = tid & 7;  // scT: 32 r-rows x 8 float4
  int brow = tid >> 4, bc4 = tid & 15; // X: 16 x-rows x 64 d (2 passes)
  float acc[2][4] = {};
  float dsum = 0.0f;
  for (int kt = 0; kt < CNX; kt += 32) {
    float4 sv = *(const float4*)(scT + ((size_t)b * CNR + r0 + arow) * CNX + kt + ak4 * 4);
    float4 ev = {fast_exp2(sv.x * L2E), fast_exp2(sv.y * L2E),
                 fast_exp2(sv.z * L2E), fast_exp2(sv.w * L2E)};
    dsum += (ev.x + ev.y) + (ev.z + ev.w);
    float4 bv0 = *(const float4*)(X + ((size_t)b * CNX + kt + brow) * CD + d0 + bc4 * 4);
    float4 bv1 = *(const float4*)(X + ((size_t)b * CNX + kt + brow + 16) * CD + d0 + bc4 * 4);
    __syncthreads();
    As[ak4 * 4 + 0][arow] = ev.x;
    As[ak4 * 4 + 1][arow] = ev.y;
    As[ak4 * 4 + 2][arow] = ev.z;
    As[ak4 * 4 + 3][arow] = ev.w;
    *(float4*)&Bs[brow][bc4 * 4] = bv0;
    *(float4*)&Bs[brow + 16][bc4 * 4] = bv1;
    __syncthreads();
#pragma unroll 8
    for (int k = 0; k < 32; k++) {
      float a0 = As[k][ty * 2], a1 = As[k][ty * 2 + 1];
      float4 b4 = *(const float4*)&Bs[k][tx * 4];
      float bm[4] = {b4.x, b4.y, b4.z, b4.w};
#pragma unroll
      for (int j = 0; j < 4; j++) {
        acc[0][j] = fmaf(a0, bm[j], acc[0][j]);
        acc[1][j] = fmaf(a1, bm[j], acc[1][j]);
      }
    }
  }
  // reduce dsum across the 8 lanes sharing a row (low 3 bits of tid)
  dsum += __shfl_xor(dsum, 1, 64);
  dsum += __shfl_xor(dsum, 2, 64);
  dsum += __shfl_xor(dsum, 4, 64);
  if ((tid & 7) == 0) dn[arow] = dsum;
  __syncthreads();
  float inv0 = fast_rcp(dn[ty * 2]);
  float inv1 = fast_rcp(dn[ty * 2 + 1]);
  float* pO = out + ((size_t)b * CNR + r0 + ty * 2) * CD + d0 + tx * 4;
  float4 o0 = {acc[0][0] * inv0, acc[0][1] * inv0, acc[0][2] * inv0, acc[0][3] * inv0};
  float4 o1 = {acc[1][0] * inv1, acc[1][1] * inv1, acc[1][2] * inv1, acc[1][3] * inv1};
  *(float4*)(pO) = o0;
  *(float4*)(pO + CD) = o1;
}

extern "C" void kernel_launch(void* const* d_in, const int* in_sizes, int n_in,
                              void* d_out, int out_size, void* d_ws, size_t ws_size,
                              hipStream_t stream) {
  const float* X     = (const float*)d_in[0];
  const float* ref   = (const float*)d_in[1];
  const float* W_X   = (const float*)d_in[2];
  const float* b_X   = (const float*)d_in[3];
  const float* W_ref = (const float*)d_in[4];
  const float* b_ref = (const float*)d_in[5];
  const float* v_w   = (const float*)d_in[6];
  float* out = (float*)d_out;
  float* ws  = (float*)d_ws;

  float* exT = ws;                       // [B][H][NX] = 1,048,576 floats
  float* erT = ws + 1048576;             // [B][H][NR] = 1,048,576 floats
  float* scT = ws + 2097152;             // [B][NR][NX] = 2,097,152 floats

  proj_fused<<<dim3(64, 4, 2), 256, 0, stream>>>(X, ref, W_X, W_ref, b_X, b_ref, exT, erT);
  scores_kernel<<<dim3(16, 16, 8), 256, 0, stream>>>(exT, erT, v_w, scT);
  wsum_fused<<<dim3(16, 4, 8), 256, 0, stream>>>(scT, X, out);
}